// Round 1
// baseline (3068.788 us; speedup 1.0000x reference)
//
#include <hip/hip_runtime.h>
#include <hip/hip_bf16.h>

#define BB 64
#define HH 256
#define LC 2048
#define LQ 256
#define NEGV -1e30f

// workspace layout in floats
#define OFF_S    0L
#define OFF_PM   33554432L            // B*LC*LQ
#define OFF_PL   33685504L            // + B*8*LQ
#define OFF_T    33816576L            // + B*8*LQ
#define OFF_FLAG 38010880L            // + B*H*LQ

template<int MODE>
__device__ __forceinline__ float ld(const void* p, long idx) {
  if (MODE == 1) {
    unsigned short u = ((const unsigned short*)p)[idx];
    return __uint_as_float(((unsigned int)u) << 16);
  } else {
    return ((const float*)p)[idx];
  }
}

__device__ __forceinline__ unsigned short f2bf(float f) {
  unsigned int u = __float_as_uint(f);
  unsigned int r = (u + 0x7fffu + ((u >> 16) & 1u)) >> 16;
  return (unsigned short)r;
}

union U16x8 { uint4 u; unsigned short s[8]; };

// ---------------- dtype sniff ----------------
// bf16 array: both 16-bit halves of each word are plausible N(0,1) bf16 values.
// fp32 array: high half plausible, low half (mantissa bits) mostly garbage exponents.
__global__ void sniff_kernel(const unsigned int* cw, int* flag) {
  __shared__ int cnt[64];
  int tid = threadIdx.x;
  unsigned int w = cw[tid];
  int p = 0;
  for (int h = 0; h < 2; h++) {
    unsigned short u = h ? (unsigned short)(w >> 16) : (unsigned short)(w & 0xffffu);
    float f = __uint_as_float(((unsigned int)u) << 16);
    float a = fabsf(f);
    if ((a >= 1e-5f && a <= 64.0f) || f == 0.0f) p++;
  }
  cnt[tid] = p;
  __syncthreads();
  if (tid == 0) {
    int t = 0;
    for (int i = 0; i < 64; i++) t += cnt[i];
    *flag = (t >= 102) ? 1 : 0;   // 1 = bf16 I/O, 0 = fp32 I/O
  }
}

// ---------------- k1: S = c1[i] + q2[j] + (Ct*w3)@Qt^T ----------------
template<int MODE>
__global__ __launch_bounds__(256) void k1_S(const void* Cp, const void* Qp, const void* lpp,
                                            float* ws, const int* flag) {
  if (*flag != MODE) return;
  __shared__ float w1s[HH], w2s[HH], w3s[HH];
  __shared__ float Cs[8][32];
  int tid = threadIdx.x;              // j
  int b = blockIdx.y;
  int i0 = blockIdx.x * 32;
  w1s[tid] = ld<MODE>(lpp, tid);
  w2s[tid] = ld<MODE>(lpp, HH + tid);
  w3s[tid] = ld<MODE>(lpp, 2 * HH + tid);
  float acc[32];
#pragma unroll
  for (int ii = 0; ii < 32; ii++) acc[ii] = 0.f;
  float q2acc = 0.f;
  long cbase = (long)b * HH * LC;
  long qbase = (long)b * HH * LQ;
  for (int hc = 0; hc < HH / 8; hc++) {
    __syncthreads();
    {
      int hh = tid >> 5, ii = tid & 31;
      Cs[hh][ii] = ld<MODE>(Cp, cbase + (long)(hc * 8 + hh) * LC + i0 + ii);
    }
    __syncthreads();
#pragma unroll
    for (int hh = 0; hh < 8; hh++) {
      int h = hc * 8 + hh;
      float qv = ld<MODE>(Qp, qbase + (long)h * LQ + tid);
      float coef = w1s[h] + w3s[h] * qv;
      q2acc += w2s[h] * qv;
#pragma unroll
      for (int ii = 0; ii < 32; ii++) acc[ii] += coef * Cs[hh][ii];
    }
  }
  float* Sout = ws + OFF_S + ((long)b * LC + i0) * LQ;
#pragma unroll
  for (int ii = 0; ii < 32; ii++)
    Sout[(long)ii * LQ + tid] = acc[ii] + q2acc;
}

// ---------------- k2a: partial column softmax stats ----------------
template<int MODE>
__global__ __launch_bounds__(256) void k2a_colpart(const void* cmaskp, const float* ws,
                                                   const int* flag) {
  if (*flag != MODE) return;
  int tid = threadIdx.x;              // j
  int b = blockIdx.y;
  int ch = blockIdx.x;                // i chunk 0..7
  const float* Sb = ws + OFF_S + ((long)b * LC + (long)ch * 256) * LQ;
  float m = -INFINITY, l = 0.f;
  for (int ii = 0; ii < 256; ii++) {
    float cm = ld<MODE>(cmaskp, (long)b * LC + ch * 256 + ii);
    float v = (cm != 0.f) ? NEGV : Sb[(long)ii * LQ + tid];
    float nm = fmaxf(m, v);
    l = l * __expf(m - nm) + __expf(v - nm);
    m = nm;
  }
  float* pm = (float*)(ws + OFF_PM);
  float* pl = (float*)(ws + OFF_PL);
  pm[((long)b * 8 + ch) * LQ + tid] = m;
  pl[((long)b * 8 + ch) * LQ + tid] = l;
}

// ---------------- k2b: Tt[b,h,j] = sum_i P_col[i,j]*C[b,h,i] ----------------
template<int MODE>
__global__ __launch_bounds__(256) void k2b_T(const void* Cp, const void* cmaskp,
                                             float* ws, const int* flag) {
  if (*flag != MODE) return;
  int tid = threadIdx.x;              // j
  int b = blockIdx.y;
  int h0 = blockIdx.x * 32;
  const float* pm = ws + OFF_PM;
  const float* pl = ws + OFF_PL;
  float M = -INFINITY;
#pragma unroll
  for (int c = 0; c < 8; c++) M = fmaxf(M, pm[((long)b * 8 + c) * LQ + tid]);
  float L = 0.f;
#pragma unroll
  for (int c = 0; c < 8; c++)
    L += pl[((long)b * 8 + c) * LQ + tid] * __expf(pm[((long)b * 8 + c) * LQ + tid] - M);
  float Linv = 1.0f / L;

  __shared__ float Cs[32][33];        // +1 pad: conflict-free staging writes
  __shared__ float cms[32];
  float acc[32];
#pragma unroll
  for (int hh = 0; hh < 32; hh++) acc[hh] = 0.f;
  long cbase = (long)b * HH * LC;
  const float* Sb = ws + OFF_S + (long)b * LC * LQ;
  for (int ic = 0; ic < LC / 32; ic++) {
    int ibase = ic * 32;
    __syncthreads();
#pragma unroll
    for (int it = 0; it < 4; it++) {
      int hh = it * 8 + (tid >> 5);
      int ii = tid & 31;
      Cs[ii][hh] = ld<MODE>(Cp, cbase + (long)(h0 + hh) * LC + ibase + ii);
    }
    if (tid < 32) cms[tid] = ld<MODE>(cmaskp, (long)b * LC + ibase + tid);
    __syncthreads();
#pragma unroll 4
    for (int ii = 0; ii < 32; ii++) {
      float sv = Sb[(long)(ibase + ii) * LQ + tid];
      float p = (cms[ii] != 0.f) ? 0.f : __expf(sv - M) * Linv;
#pragma unroll
      for (int hh = 0; hh < 32; hh++) acc[hh] += p * Cs[ii][hh];
    }
  }
  float* To = ws + OFF_T + ((long)b * HH + h0) * LQ;
#pragma unroll
  for (int hh = 0; hh < 32; hh++)
    To[(long)hh * LQ + tid] = acc[hh];
}

// ---------------- k3: row softmax + A + Bt + fused output ----------------
template<int MODE>
__global__ __launch_bounds__(256) void k3_out(const void* Cp, const void* Qp, const void* qmaskp,
                                              const float* ws, void* outp, const int* flag) {
  if (*flag != MODE) return;
  __shared__ __align__(16) float Pst[LQ][36];   // stride 36 floats = 144B (16B aligned rows)
  __shared__ float qms[LQ];
  __shared__ float red[32][8];
  __shared__ float rowm[32], rowinv[32];
  int tid = threadIdx.x;
  int b = blockIdx.y;
  int i0 = blockIdx.x * 32;
  qms[tid] = ld<MODE>(qmaskp, (long)b * LQ + tid);
  __syncthreads();

  // phase 1: row softmax for 32 rows; 8 threads per row
  int r = tid >> 3, s = tid & 7;
  const float* Srow = ws + OFF_S + ((long)b * LC + i0 + r) * LQ;
  float m = -INFINITY;
#pragma unroll 4
  for (int k = 0; k < 32; k++) {
    int j = k * 8 + s;
    float v = (qms[j] != 0.f) ? NEGV : Srow[j];
    m = fmaxf(m, v);
  }
  red[r][s] = m;
  __syncthreads();
  if (s == 0) {
    float mm = red[r][0];
#pragma unroll
    for (int t = 1; t < 8; t++) mm = fmaxf(mm, red[r][t]);
    rowm[r] = mm;
  }
  __syncthreads();
  float rm = rowm[r];
  float l = 0.f;
#pragma unroll 4
  for (int k = 0; k < 32; k++) {
    int j = k * 8 + s;
    float v = (qms[j] != 0.f) ? NEGV : Srow[j];
    float e = __expf(v - rm);
    Pst[j][r] = e;
    l += e;
  }
  red[r][s] = l;
  __syncthreads();
  if (s == 0) {
    float ll = 0.f;
#pragma unroll
    for (int t = 0; t < 8; t++) ll += red[r][t];
    rowinv[r] = 1.0f / ll;
  }
  __syncthreads();
  float ri = rowinv[r];
#pragma unroll 4
  for (int k = 0; k < 32; k++) Pst[k * 8 + s][r] *= ri;
  __syncthreads();

  // phase 2: thread = h; A[i,h] = sum_j P[i,j]Q[h,j]; Bt[i,h] = sum_j P[i,j]Tt[h,j]
  float accA[32], accB[32];
#pragma unroll
  for (int ii = 0; ii < 32; ii++) { accA[ii] = 0.f; accB[ii] = 0.f; }
  long qbase = ((long)b * HH + tid) * LQ;
  const float* Trow = ws + OFF_T + ((long)b * HH + tid) * LQ;
  for (int j = 0; j < LQ; j++) {
    float qv = ld<MODE>(Qp, qbase + j);
    float tv = Trow[j];
    const float4* pj = (const float4*)&Pst[j][0];
#pragma unroll
    for (int q = 0; q < 8; q++) {
      float4 pv = pj[q];
      accA[q * 4 + 0] += qv * pv.x;  accB[q * 4 + 0] += tv * pv.x;
      accA[q * 4 + 1] += qv * pv.y;  accB[q * 4 + 1] += tv * pv.y;
      accA[q * 4 + 2] += qv * pv.z;  accB[q * 4 + 2] += tv * pv.z;
      accA[q * 4 + 3] += qv * pv.w;  accB[q * 4 + 3] += tv * pv.w;
    }
  }

  // epilogue: out = [Ct | A | Ct*A | Ct*Bt] transposed to (4H, LC)
  long cbase = ((long)b * HH + tid) * LC + i0;
  float cv[32];
#pragma unroll
  for (int ii = 0; ii < 32; ii++) cv[ii] = ld<MODE>(Cp, cbase + ii);

  long ob = (long)b * (4 * HH) * LC;
  if (MODE == 1) {
    unsigned short* o = (unsigned short*)outp;
    unsigned short* r0 = o + ob + (long)tid * LC + i0;
    unsigned short* r1 = o + ob + (long)(HH + tid) * LC + i0;
    unsigned short* r2 = o + ob + (long)(2 * HH + tid) * LC + i0;
    unsigned short* r3 = o + ob + (long)(3 * HH + tid) * LC + i0;
#pragma unroll
    for (int c = 0; c < 4; c++) {
      U16x8 o0, o1, o2, o3;
#pragma unroll
      for (int t = 0; t < 8; t++) {
        int ii = c * 8 + t;
        float a = accA[ii], bb = accB[ii], cc = cv[ii];
        o0.s[t] = f2bf(cc);
        o1.s[t] = f2bf(a);
        o2.s[t] = f2bf(cc * a);
        o3.s[t] = f2bf(cc * bb);
      }
      ((uint4*)r0)[c] = o0.u;
      ((uint4*)r1)[c] = o1.u;
      ((uint4*)r2)[c] = o2.u;
      ((uint4*)r3)[c] = o3.u;
    }
  } else {
    float* o = (float*)outp;
    float* r0 = o + ob + (long)tid * LC + i0;
    float* r1 = o + ob + (long)(HH + tid) * LC + i0;
    float* r2 = o + ob + (long)(2 * HH + tid) * LC + i0;
    float* r3 = o + ob + (long)(3 * HH + tid) * LC + i0;
#pragma unroll
    for (int c = 0; c < 8; c++) {
      int ii = c * 4;
      float4 v0 = make_float4(cv[ii], cv[ii + 1], cv[ii + 2], cv[ii + 3]);
      float4 v1 = make_float4(accA[ii], accA[ii + 1], accA[ii + 2], accA[ii + 3]);
      float4 v2 = make_float4(cv[ii] * accA[ii], cv[ii + 1] * accA[ii + 1],
                              cv[ii + 2] * accA[ii + 2], cv[ii + 3] * accA[ii + 3]);
      float4 v3 = make_float4(cv[ii] * accB[ii], cv[ii + 1] * accB[ii + 1],
                              cv[ii + 2] * accB[ii + 2], cv[ii + 3] * accB[ii + 3]);
      ((float4*)r0)[c] = v0;
      ((float4*)r1)[c] = v1;
      ((float4*)r2)[c] = v2;
      ((float4*)r3)[c] = v3;
    }
  }
}

extern "C" void kernel_launch(void* const* d_in, const int* in_sizes, int n_in,
                              void* d_out, int out_size, void* d_ws, size_t ws_size,
                              hipStream_t stream) {
  const void* C  = d_in[0];
  const void* Q  = d_in[1];
  const void* cm = d_in[2];
  const void* qm = d_in[3];
  const void* lp = d_in[4];
  float* ws = (float*)d_ws;
  int* flag = (int*)(ws + OFF_FLAG);

  sniff_kernel<<<1, 64, 0, stream>>>((const unsigned int*)C, flag);

  dim3 g1(LC / 32, BB), g2a(8, BB), g2b(HH / 32, BB), g3(LC / 32, BB);

  k1_S<1><<<g1, 256, 0, stream>>>(C, Q, lp, ws, flag);
  k1_S<0><<<g1, 256, 0, stream>>>(C, Q, lp, ws, flag);

  k2a_colpart<1><<<g2a, 256, 0, stream>>>(cm, ws, flag);
  k2a_colpart<0><<<g2a, 256, 0, stream>>>(cm, ws, flag);

  k2b_T<1><<<g2b, 256, 0, stream>>>(C, cm, ws, flag);
  k2b_T<0><<<g2b, 256, 0, stream>>>(C, cm, ws, flag);

  k3_out<1><<<g3, 256, 0, stream>>>(C, Q, qm, ws, d_out, flag);
  k3_out<0><<<g3, 256, 0, stream>>>(C, Q, qm, ws, d_out, flag);
}